// Round 9
// baseline (277.648 us; speedup 1.0000x reference)
//
#include <hip/hip_runtime.h>
#include <cstdint>

#define TOPK 2000
#define NMS_THR 0.5f
#define NCLS 21
#define HSHIFT 14
#define HBINS (1u << 16)   // scores<1.0 => bits>>14 <= 65024 < 2^16. Bin width unchanged.
#define NCHUNK 256         // HBINS/256
#define CAND_CAP 4096
#define TPAD 2048

typedef unsigned long long u64;
typedef unsigned int u32;
typedef float f32x4 __attribute__((ext_vector_type(4)));  // native vec for NT stores

// Histogram storage permutation: adjacent bins -> 1KB apart (distinct L2
// lines/slices). Kills cross-XCD ownership ping-pong on hot-line clusters.
__device__ __forceinline__ u32 hperm(u32 bin) { return ((bin & 255u) << 8) | (bin >> 8); }

// IoU exactly as reference get_iou. contract(off) to match numpy rounding.
__device__ __forceinline__ float iou_pair(float ax1, float ay1, float ax2, float ay2, float aarea,
                                          float bx1, float by1, float bx2, float by2, float barea) {
#pragma clang fp contract(off)
    float ltx = fmaxf(ax1, bx1), lty = fmaxf(ay1, by1);
    float rbx = fminf(ax2, bx2), rby = fminf(ay2, by2);
    float wx = fmaxf(rbx - ltx, 0.f), wy = fmaxf(rby - lty, 0.f);
    float inter = wx * wy;
    return inter / (aarea + barea - inter);
}

// k_prep: transpose cls [N][21] -> clsT [21][N] (coalesced softmax reads in
// k_main); zero hist/csum/meta/rank.
__global__ __launch_bounds__(256) void k_prep(const float* __restrict__ cls,
                                              float* __restrict__ clsT,
                                              u32* __restrict__ hist, u32* __restrict__ csum,
                                              u32* __restrict__ meta, u32* __restrict__ rank,
                                              int N) {
    __shared__ float slds[256 * NCLS];
    int b = blockIdx.x, t = threadIdx.x;

    for (int v = b * 256 + t; v < (int)(HBINS / 4); v += gridDim.x * 256)
        ((uint4*)hist)[v] = make_uint4(0u, 0u, 0u, 0u);
    if (b == 0) {
        csum[t] = 0u;
        if (t < 64) meta[t] = 0u;
    }
    if (b < 16) rank[b * 256 + t] = 0u;

    int row0 = b * 256;
    int rows = N - row0;
    if (rows <= 0) return;
    if (rows > 256) rows = 256;
    if (rows == 256) {
        const uint4* __restrict__ src = (const uint4*)(cls + (size_t)row0 * NCLS);
        uint4* __restrict__ dst = (uint4*)slds;
        for (int v = t; v < 1344; v += 256) dst[v] = src[v];  // 256*21/4
    } else {
        int nw = rows * NCLS;
        const float* __restrict__ src = cls + (size_t)row0 * NCLS;
        for (int v = t; v < nw; v += 256) slds[v] = src[v];
    }
    __syncthreads();
    if (t < rows) {
#pragma unroll
        for (int c = 0; c < NCLS; ++c)
            clsT[(size_t)c * N + row0 + t] = slds[t * NCLS + c];
    }
}

// Per-proposal main (R8 body: coalesced clsT reads + permuted hist).
__global__ __launch_bounds__(256, 3) void k_main(
    const float* __restrict__ prop, const float* __restrict__ btp,
    const float* __restrict__ clsT, const float* __restrict__ gt,
    const int* __restrict__ hptr, const int* __restrict__ wptr,
    float* __restrict__ out, float4* __restrict__ box_per,
    u32* __restrict__ score_bits, u32* __restrict__ hist,
    int N, int G) {
#pragma clang fp contract(off)
    __shared__ float4 sgt[256];
    __shared__ float sga[256];
    int tid = threadIdx.x;
    for (int g = tid; g < G; g += 256) {
        float4 gb = ((const float4*)gt)[g];
        sgt[g] = gb;
        sga[g] = (gb.z - gb.x) * (gb.w - gb.y);
    }
    __syncthreads();

    int i = blockIdx.x * 256 + tid;
    if (i >= N) return;

    float W = (float)wptr[0], H = (float)hptr[0];
    float4 p = ((const float4*)prop)[i];
    float pw = p.z - p.x, ph = p.w - p.y;
    float pcx = p.x + 0.5f * pw, pcy = p.y + 0.5f * ph;

    float e[NCLS];
#pragma unroll
    for (int c = 0; c < NCLS; ++c) e[c] = clsT[(size_t)c * N + i];

    float m = e[0];
#pragma unroll
    for (int c = 1; c < NCLS; ++c) m = fmaxf(m, e[c]);
#pragma unroll
    for (int c = 0; c < NCLS; ++c) e[c] = expf(e[c] - m);
    float Z = 0.f;
#pragma unroll
    for (int c = 0; c < NCLS; ++c) Z += e[c];
    float best = -1.f;
    int bc = 1;
#pragma unroll
    for (int c = 1; c < NCLS; ++c) {
        float pr = e[c] / Z;  // same op sequence as reference softmax+max
        if (pr > best) { best = pr; bc = c; }
    }

    float4 t = ((const float4*)btp)[(size_t)i * NCLS + bc];

    u32 b = __float_as_uint(best);
    score_bits[i] = b;
    atomicAdd(&hist[hperm(b >> HSHIFT)], 1u);

    float parea = pw * ph;
    float bestiou = -1.f;
    int bi = 0;
    int g = 0;
    for (; g + 8 <= G; g += 8) {
        float4 g0 = sgt[g], g1 = sgt[g + 1], g2 = sgt[g + 2], g3 = sgt[g + 3];
        float4 g4 = sgt[g + 4], g5 = sgt[g + 5], g6 = sgt[g + 6], g7 = sgt[g + 7];
        float a0 = sga[g], a1 = sga[g + 1], a2 = sga[g + 2], a3 = sga[g + 3];
        float a4 = sga[g + 4], a5 = sga[g + 5], a6 = sga[g + 6], a7 = sga[g + 7];
        float v0 = iou_pair(g0.x, g0.y, g0.z, g0.w, a0, p.x, p.y, p.z, p.w, parea);
        float v1 = iou_pair(g1.x, g1.y, g1.z, g1.w, a1, p.x, p.y, p.z, p.w, parea);
        float v2 = iou_pair(g2.x, g2.y, g2.z, g2.w, a2, p.x, p.y, p.z, p.w, parea);
        float v3 = iou_pair(g3.x, g3.y, g3.z, g3.w, a3, p.x, p.y, p.z, p.w, parea);
        float v4 = iou_pair(g4.x, g4.y, g4.z, g4.w, a4, p.x, p.y, p.z, p.w, parea);
        float v5 = iou_pair(g5.x, g5.y, g5.z, g5.w, a5, p.x, p.y, p.z, p.w, parea);
        float v6 = iou_pair(g6.x, g6.y, g6.z, g6.w, a6, p.x, p.y, p.z, p.w, parea);
        float v7 = iou_pair(g7.x, g7.y, g7.z, g7.w, a7, p.x, p.y, p.z, p.w, parea);
        float va = v0; int ia = g;
        if (v1 > va) { va = v1; ia = g + 1; }
        float vb = v2; int ib = g + 2;
        if (v3 > vb) { vb = v3; ib = g + 3; }
        if (vb > va) { va = vb; ia = ib; }
        float vc = v4; int ic = g + 4;
        if (v5 > vc) { vc = v5; ic = g + 5; }
        float vd = v6; int id_ = g + 6;
        if (v7 > vd) { vd = v7; id_ = g + 7; }
        if (vd > vc) { vc = vd; ic = id_; }
        if (vc > va) { va = vc; ia = ic; }
        if (va > bestiou) { bestiou = va; bi = ia; }
    }
    for (; g < G; ++g) {
        float4 gb = sgt[g];
        float v = iou_pair(gb.x, gb.y, gb.z, gb.w, sga[g], p.x, p.y, p.z, p.w, parea);
        if (v > bestiou) { bestiou = v; bi = g; }
    }

    float qcx = t.x * pw + pcx, qcy = t.y * ph + pcy;
    float qw = expf(t.z) * pw, qh = expf(t.w) * ph;
    float bx1 = fminf(fmaxf(qcx - 0.5f * qw, 0.f), W);
    float by1 = fminf(fmaxf(qcy - 0.5f * qh, 0.f), H);
    float bx2 = fminf(fmaxf(qcx + 0.5f * qw, 0.f), W);
    float by2 = fminf(fmaxf(qcy + 0.5f * qh, 0.f), H);
    f32x4 bp = {bx1, by1, bx2, by2};
    __builtin_nontemporal_store(bp, (f32x4*)&box_per[i]);

    float4 mg = sgt[bi];
    float gw = mg.z - mg.x, gh = mg.w - mg.y;
    float gcx = mg.x + 0.5f * gw, gcy = mg.y + 0.5f * gh;
    f32x4 rt = {(gcx - pcx) / pw, (gcy - pcy) / ph, logf(gw / pw), logf(gh / ph)};
    __builtin_nontemporal_store(rt, (f32x4*)(out + 4 * (size_t)(TOPK + i)));
}

// 256 blocks: per-chunk sums via device-scope atomics; LAST block runs the
// threshold-bin scan in-block (hist addressed through hperm).
__global__ __launch_bounds__(256) void k_hsum_scan(const u32* __restrict__ hist,
                                                   u32* __restrict__ csum,
                                                   u32* __restrict__ meta) {
    __shared__ u32 ps[4];
    __shared__ u32 S[NCHUNK];
    __shared__ u32 sh_tc, sh_E;
    __shared__ int slast;
    int b = blockIdx.x, t = threadIdx.x;

    u32 v = hist[(size_t)t * 256 + b];  // hperm(b*256+t)
#pragma unroll
    for (int o = 32; o; o >>= 1) v += __shfl_xor(v, o);
    if ((t & 63) == 0) ps[t >> 6] = v;
    __syncthreads();
    if (t == 0) {
        u32 tot = ps[0] + ps[1] + ps[2] + ps[3];
        atomicAdd(&csum[b], tot);
        __threadfence();
        u32 old = atomicAdd(&meta[62], 1u);
        slast = (old == NCHUNK - 1u) ? 1 : 0;
    }
    __syncthreads();
    if (!slast) return;

    u32 c = atomicAdd(&csum[t], 0u);
    S[t] = c;
    __syncthreads();
    for (int off = 1; off < NCHUNK; off <<= 1) {
        u32 x = (t + off < NCHUNK) ? S[t + off] : 0u;
        __syncthreads();
        S[t] += x;
        __syncthreads();
    }
    u32 suff = S[t];
    u32 E = suff - c;
    if (suff >= TOPK && E < TOPK) { sh_tc = (u32)t; sh_E = E; }
    __syncthreads();
    u32 tc = sh_tc, E0 = sh_E;
    u32 hh = hist[(size_t)t * 256 + tc];  // hperm(tc*256+t)
    __syncthreads();
    S[t] = hh;
    __syncthreads();
    for (int off = 1; off < NCHUNK; off <<= 1) {
        u32 x = (t + off < NCHUNK) ? S[t + off] : 0u;
        __syncthreads();
        S[t] += x;
        __syncthreads();
    }
    u32 tot2 = E0 + S[t];
    if (tot2 >= TOPK && (tot2 - hh) < TOPK) meta[0] = tc * 256u + (u32)t;
}

__global__ __launch_bounds__(256) void k_compact(const u32* __restrict__ score_bits,
                                                 const u32* __restrict__ meta, u32* __restrict__ cnt,
                                                 u64* __restrict__ keys, int N) {
    int i = blockIdx.x * 256 + threadIdx.x;
    if (i >= N) return;
    u32 b = score_bits[i];
    if ((b >> HSHIFT) >= meta[0]) {
        u32 pos = atomicAdd(cnt, 1u);
        if (pos < CAND_CAP) keys[pos] = ((u64)b << 32) | (u32)(~(u32)i);
    }
}

// Rank partials: 256 blocks = 16 i-tiles x 16 j-slices.
__global__ __launch_bounds__(256) void k_rank1(const u64* __restrict__ keys,
                                               const u32* __restrict__ meta,
                                               u32* __restrict__ rank) {
    __shared__ u64 sk[256];
    int it = blockIdx.x & 15, js = blockIdx.x >> 4;
    int t = threadIdx.x;
    u32 M = meta[1];
    if (M > CAND_CAP) M = CAND_CAP;
    u32 Mp = (M + 63u) & ~63u;
    u32 j0 = (u32)js * 256u;
    if (j0 >= Mp) return;
    u32 jn = Mp - j0; if (jn > 256u) jn = 256u;
    sk[t] = ((u32)t < jn && j0 + t < M) ? keys[j0 + t] : 0ull;
    __syncthreads();
    int idx = it * 256 + t;
    u64 k = (idx < (int)M) ? keys[idx] : ~0ull;
    u32 r = 0;
    int lane = t & 63;
    for (u32 jj = 0; jj < jn; jj += 64) {
        u64 tv = sk[jj + lane];
        u32 tlo = (u32)tv, thi = (u32)(tv >> 32);
#pragma unroll
        for (int l = 0; l < 64; ++l) {
            u64 kj = ((u64)(u32)__builtin_amdgcn_readlane(thi, l) << 32) |
                     (u64)(u32)__builtin_amdgcn_readlane(tlo, l);
            r += (kj > k) ? 1u : 0u;
        }
    }
    if (idx < (int)M && r) atomicAdd(&rank[idx], r);
}

__global__ __launch_bounds__(256) void k_rank2(const u64* __restrict__ keys,
                                               const u32* __restrict__ meta,
                                               const u32* __restrict__ rank,
                                               const float4* __restrict__ box_per,
                                               float4* __restrict__ topbox) {
    int idx = blockIdx.x * 256 + threadIdx.x;
    u32 M = meta[1];
    if (M > CAND_CAP) M = CAND_CAP;
    if (idx >= (int)M) return;
    u32 r = rank[idx];
    if (r < TOPK) {
        u64 k = keys[idx];
        topbox[r] = box_per[~(u32)(k & 0xffffffffull)];
    }
}

// Suppression mask, ROW-major. Additionally writes diag[i] = the word of row
// i that contains row i's own 64-block (for k_nms phase-1 closure).
__global__ __launch_bounds__(256) void k_mask(const float4* __restrict__ topbox,
                                              u64* __restrict__ mask,
                                              u64* __restrict__ diag) {
#pragma clang fp contract(off)
    int gid = blockIdx.x * 256 + threadIdx.x;  // 32 * TPAD threads
    int w = gid >> 11, i = gid & (TPAD - 1);
    u64 m = 0;
    int j0 = w << 6;
    if (i < TOPK && j0 + 63 > i) {
        float4 a = topbox[i];
        float aarea = (a.z - a.x) * (a.w - a.y);
        for (int jj = 0; jj < 64; ++jj) {
            int j = j0 + jj;
            if (j < TOPK && j > i) {
                float4 b = topbox[j];
                float barea = (b.z - b.x) * (b.w - b.y);
                float v = iou_pair(a.x, a.y, a.z, a.w, aarea, b.x, b.y, b.z, b.w, barea);
                if (v > NMS_THR) m |= (1ull << jj);
            }
        }
    }
    mask[(size_t)i * 32 + w] = m;
    if (w == (i >> 6)) diag[i] = m;  // unconditional: rows past TOPK get 0
}

// Greedy NMS, restructured (R9). Old consumer: 2048 serial steps x ~80cyc
// (LDS ring load + readlanes INSIDE the serial chain; lgkmcnt collapse) =
// ~70us. New: per 64-chunk, (1) serial closure over the DIAGONAL 64x64 block
// only -- diag words live in registers, readlane with constant lane after
// unroll, ~6 SALU/step, no memory on the chain; kept bits are final because
// row l' only sets bits j>l'. (2) parallel OR of kept rows into the removed
// set: 32 independent LDS b64 loads/lane (pipelineable), rows split across
// the two 32-lane halves (lane 32+w holds a second copy of word w; combined
// by shfl_xor(32) at the end). Producers (waves 1-2) unchanged.
__global__ __launch_bounds__(256) void k_nms(const u64* __restrict__ mask,
                                             const u64* __restrict__ diag,
                                             const float4* __restrict__ topbox,
                                             float* __restrict__ out) {
    __shared__ u64 sm[2][64 * 32];  // 2 x 16 KB double buffer
    __shared__ u64 srem[32];
    int t = threadIdx.x;
    int lane = t & 63;
    int half = (lane >> 5) & 1;     // 0: rows 0-31 of chunk, 1: rows 32-63
    u32 lw = (u32)(lane & 31);      // removed-set word owned by this lane
    u32 rlo = 0, rhi = 0;           // this lane's half-copy of word lw

    // stage chunk 0: all 256 threads, 4 unconditional uint4 each
    {
        const uint4* __restrict__ src = (const uint4*)mask;
        uint4 v0 = src[t], v1 = src[t + 256], v2 = src[t + 512], v3 = src[t + 768];
        uint4* __restrict__ dst = (uint4*)sm[0];
        dst[t] = v0; dst[t + 256] = v1; dst[t + 512] = v2; dst[t + 768] = v3;
    }
    u64 dg_cur = 0, dg_nxt = 0;
    if (t < 64) dg_cur = diag[lane];  // chunk-0 diag prefetch (overlaps staging)
    __syncthreads();

    for (int c = 0; c < 32; ++c) {
        if (t >= 64 && t < 192) {
            if (c + 1 < 32) {
                const uint4* __restrict__ src = (const uint4*)(mask + (size_t)(c + 1) * 2048);
                uint4* __restrict__ dst = (uint4*)sm[(c + 1) & 1];
                int u = t - 64;  // 0..127; 8 unconditional slots cover 1024 uint4
                uint4 v0 = src[u];
                uint4 v1 = src[u + 128];
                uint4 v2 = src[u + 256];
                uint4 v3 = src[u + 384];
                uint4 v4 = src[u + 512];
                uint4 v5 = src[u + 640];
                uint4 v6 = src[u + 768];
                uint4 v7 = src[u + 896];
                dst[u] = v0;
                dst[u + 128] = v1;
                dst[u + 256] = v2;
                dst[u + 384] = v3;
                dst[u + 512] = v4;
                dst[u + 640] = v5;
                dst[u + 768] = v6;
                dst[u + 896] = v7;
            }
        } else if (t < 64) {
            if (c + 1 < 32) dg_nxt = diag[(c + 1) * 64 + lane];  // latency hidden
            const u64* __restrict__ buf = sm[c & 1];

            // ---- phase 1: serial closure on the diagonal block ----
            u32 dgl = (u32)dg_cur, dgh = (u32)(dg_cur >> 32);
            u32 d_lo = (u32)__builtin_amdgcn_readlane(rlo, c) |
                       (u32)__builtin_amdgcn_readlane(rlo, c + 32);
            u32 d_hi = (u32)__builtin_amdgcn_readlane(rhi, c) |
                       (u32)__builtin_amdgcn_readlane(rhi, c + 32);
#pragma unroll
            for (int l = 0; l < 64; ++l) {
                u32 sc_lo = (u32)__builtin_amdgcn_readlane(dgl, l);
                u32 sc_hi = (u32)__builtin_amdgcn_readlane(dgh, l);
                u32 bit = (l < 32) ? ((d_lo >> l) & 1u) : ((d_hi >> (l - 32)) & 1u);
                u32 mk = bit - 1u;  // keep -> all-ones
                d_lo |= sc_lo & mk;
                d_hi |= sc_hi & mk;
            }

            // ---- phase 2: parallel OR of kept rows (this lane's half) ----
            u32 kept = half ? ~d_hi : ~d_lo;  // bit k: row half*32+k kept
            int rbase = half << 5;
#pragma unroll
            for (int k = 0; k < 32; ++k) {
                u64 row = buf[(rbase + k) * 32 + lw];
                u32 mk = 0u - ((kept >> k) & 1u);
                rlo |= (u32)row & mk;
                rhi |= (u32)(row >> 32) & mk;
            }
            dg_cur = dg_nxt;
        }
        __syncthreads();
    }
    if (t < 64) {
        u32 flo = rlo | (u32)__shfl_xor((int)rlo, 32);
        u32 fhi = rhi | (u32)__shfl_xor((int)rhi, 32);
        if (t < 32) srem[t] = ((u64)fhi << 32) | flo;
    }
    __syncthreads();
    for (int r = t; r < TOPK; r += 256) {
        bool sup = (srem[r >> 6] >> (r & 63)) & 1ull;
        float4 b = topbox[r];
        ((float4*)out)[r] = sup ? make_float4(0.f, 0.f, 0.f, 0.f) : b;
    }
}

extern "C" void kernel_launch(void* const* d_in, const int* in_sizes, int n_in,
                              void* d_out, int out_size, void* d_ws, size_t ws_size,
                              hipStream_t stream) {
    const float* prop = (const float*)d_in[0];
    const float* btp = (const float*)d_in[1];
    const float* cls = (const float*)d_in[2];
    const float* gt = (const float*)d_in[3];
    const int* hptr = (const int*)d_in[4];
    const int* wptr = (const int*)d_in[5];
    float* out = (float*)d_out;
    int N = in_sizes[0] / 4;
    int G = in_sizes[3] / 4;
    if (G > 256) G = 256;

    char* ws = (char*)d_ws;
    size_t o = 0;
    u32* hist = (u32*)(ws + o);       o += (size_t)HBINS * 4;
    u32* csum = (u32*)(ws + o);       o += NCHUNK * 4;
    u32* meta = (u32*)(ws + o);       o += 256;
    u32* rank = (u32*)(ws + o);       o += (size_t)CAND_CAP * 4;
    u32* score_bits = (u32*)(ws + o); o += (((size_t)N * 4 + 255) & ~(size_t)255);
    u64* keys = (u64*)(ws + o);       o += (size_t)CAND_CAP * 8;
    float4* box_per = (float4*)(ws + o); o += (size_t)N * 16;
    float4* topbox = (float4*)(ws + o);  o += (size_t)TPAD * 16;
    u64* mask = (u64*)(ws + o);       o += (size_t)TPAD * 32 * 8;
    u64* diag = (u64*)(ws + o);       o += (size_t)TPAD * 8;
    float* clsT = (float*)(ws + o);   o += (size_t)N * NCLS * 4;
    (void)o; (void)ws_size; (void)n_in; (void)out_size;

    int nb = (N + 255) / 256;
    k_prep<<<nb, 256, 0, stream>>>(cls, clsT, hist, csum, meta, rank, N);
    k_main<<<nb, 256, 0, stream>>>(prop, btp, clsT, gt, hptr, wptr, out, box_per, score_bits,
                                   hist, N, G);
    k_hsum_scan<<<NCHUNK, 256, 0, stream>>>(hist, csum, meta);
    k_compact<<<nb, 256, 0, stream>>>(score_bits, meta, meta + 1, keys, N);
    k_rank1<<<256, 256, 0, stream>>>(keys, meta, rank);
    k_rank2<<<CAND_CAP / 256, 256, 0, stream>>>(keys, meta, rank, box_per, topbox);
    k_mask<<<(32 * TPAD) / 256, 256, 0, stream>>>(topbox, mask, diag);
    k_nms<<<1, 256, 0, stream>>>(mask, diag, topbox, out);
}

// Round 10
// 236.687 us; speedup vs baseline: 1.1731x; 1.1731x over previous
//
#include <hip/hip_runtime.h>
#include <cstdint>

#define TOPK 2000
#define NMS_THR 0.5f
#define NCLS 21
#define HSHIFT 14
#define HBINS (1u << 16)   // scores<1.0 => bits>>14 <= 65024 < 2^16. Bin width unchanged.
#define NCHUNK 256         // HBINS/256
#define CAND_CAP 4096
#define TPAD 2048

typedef unsigned long long u64;
typedef unsigned int u32;
typedef float f32x4 __attribute__((ext_vector_type(4)));  // native vec for NT stores

// Histogram storage permutation: adjacent bins -> 1KB apart (distinct L2
// lines/slices). Kills cross-XCD ownership ping-pong on hot-line clusters.
__device__ __forceinline__ u32 hperm(u32 bin) { return ((bin & 255u) << 8) | (bin >> 8); }

// IoU exactly as reference get_iou. contract(off) to match numpy rounding.
__device__ __forceinline__ float iou_pair(float ax1, float ay1, float ax2, float ay2, float aarea,
                                          float bx1, float by1, float bx2, float by2, float barea) {
#pragma clang fp contract(off)
    float ltx = fmaxf(ax1, bx1), lty = fmaxf(ay1, by1);
    float rbx = fminf(ax2, bx2), rby = fminf(ay2, by2);
    float wx = fmaxf(rbx - ltx, 0.f), wy = fmaxf(rby - lty, 0.f);
    float inter = wx * wy;
    return inter / (aarea + barea - inter);
}

// k_prep: transpose cls [N][21] -> clsT [21][N] (coalesced softmax reads in
// k_main); zero hist/csum/meta/rank.
__global__ __launch_bounds__(256) void k_prep(const float* __restrict__ cls,
                                              float* __restrict__ clsT,
                                              u32* __restrict__ hist, u32* __restrict__ csum,
                                              u32* __restrict__ meta, u32* __restrict__ rank,
                                              int N) {
    __shared__ float slds[256 * NCLS];
    int b = blockIdx.x, t = threadIdx.x;

    for (int v = b * 256 + t; v < (int)(HBINS / 4); v += gridDim.x * 256)
        ((uint4*)hist)[v] = make_uint4(0u, 0u, 0u, 0u);
    if (b == 0) {
        csum[t] = 0u;
        if (t < 64) meta[t] = 0u;
    }
    if (b < 16) rank[b * 256 + t] = 0u;

    int row0 = b * 256;
    int rows = N - row0;
    if (rows <= 0) return;
    if (rows > 256) rows = 256;
    if (rows == 256) {
        const uint4* __restrict__ src = (const uint4*)(cls + (size_t)row0 * NCLS);
        uint4* __restrict__ dst = (uint4*)slds;
        for (int v = t; v < 1344; v += 256) dst[v] = src[v];  // 256*21/4
    } else {
        int nw = rows * NCLS;
        const float* __restrict__ src = cls + (size_t)row0 * NCLS;
        for (int v = t; v < nw; v += 256) slds[v] = src[v];
    }
    __syncthreads();
    if (t < rows) {
#pragma unroll
        for (int c = 0; c < NCLS; ++c)
            clsT[(size_t)c * N + row0 + t] = slds[t * NCLS + c];
    }
}

// Per-proposal main (R8 body: coalesced clsT reads + permuted hist).
__global__ __launch_bounds__(256, 3) void k_main(
    const float* __restrict__ prop, const float* __restrict__ btp,
    const float* __restrict__ clsT, const float* __restrict__ gt,
    const int* __restrict__ hptr, const int* __restrict__ wptr,
    float* __restrict__ out, float4* __restrict__ box_per,
    u32* __restrict__ score_bits, u32* __restrict__ hist,
    int N, int G) {
#pragma clang fp contract(off)
    __shared__ float4 sgt[256];
    __shared__ float sga[256];
    int tid = threadIdx.x;
    for (int g = tid; g < G; g += 256) {
        float4 gb = ((const float4*)gt)[g];
        sgt[g] = gb;
        sga[g] = (gb.z - gb.x) * (gb.w - gb.y);
    }
    __syncthreads();

    int i = blockIdx.x * 256 + tid;
    if (i >= N) return;

    float W = (float)wptr[0], H = (float)hptr[0];
    float4 p = ((const float4*)prop)[i];
    float pw = p.z - p.x, ph = p.w - p.y;
    float pcx = p.x + 0.5f * pw, pcy = p.y + 0.5f * ph;

    float e[NCLS];
#pragma unroll
    for (int c = 0; c < NCLS; ++c) e[c] = clsT[(size_t)c * N + i];

    float m = e[0];
#pragma unroll
    for (int c = 1; c < NCLS; ++c) m = fmaxf(m, e[c]);
#pragma unroll
    for (int c = 0; c < NCLS; ++c) e[c] = expf(e[c] - m);
    float Z = 0.f;
#pragma unroll
    for (int c = 0; c < NCLS; ++c) Z += e[c];
    float best = -1.f;
    int bc = 1;
#pragma unroll
    for (int c = 1; c < NCLS; ++c) {
        float pr = e[c] / Z;  // same op sequence as reference softmax+max
        if (pr > best) { best = pr; bc = c; }
    }

    float4 t = ((const float4*)btp)[(size_t)i * NCLS + bc];

    u32 b = __float_as_uint(best);
    score_bits[i] = b;
    atomicAdd(&hist[hperm(b >> HSHIFT)], 1u);

    float parea = pw * ph;
    float bestiou = -1.f;
    int bi = 0;
    int g = 0;
    for (; g + 8 <= G; g += 8) {
        float4 g0 = sgt[g], g1 = sgt[g + 1], g2 = sgt[g + 2], g3 = sgt[g + 3];
        float4 g4 = sgt[g + 4], g5 = sgt[g + 5], g6 = sgt[g + 6], g7 = sgt[g + 7];
        float a0 = sga[g], a1 = sga[g + 1], a2 = sga[g + 2], a3 = sga[g + 3];
        float a4 = sga[g + 4], a5 = sga[g + 5], a6 = sga[g + 6], a7 = sga[g + 7];
        float v0 = iou_pair(g0.x, g0.y, g0.z, g0.w, a0, p.x, p.y, p.z, p.w, parea);
        float v1 = iou_pair(g1.x, g1.y, g1.z, g1.w, a1, p.x, p.y, p.z, p.w, parea);
        float v2 = iou_pair(g2.x, g2.y, g2.z, g2.w, a2, p.x, p.y, p.z, p.w, parea);
        float v3 = iou_pair(g3.x, g3.y, g3.z, g3.w, a3, p.x, p.y, p.z, p.w, parea);
        float v4 = iou_pair(g4.x, g4.y, g4.z, g4.w, a4, p.x, p.y, p.z, p.w, parea);
        float v5 = iou_pair(g5.x, g5.y, g5.z, g5.w, a5, p.x, p.y, p.z, p.w, parea);
        float v6 = iou_pair(g6.x, g6.y, g6.z, g6.w, a6, p.x, p.y, p.z, p.w, parea);
        float v7 = iou_pair(g7.x, g7.y, g7.z, g7.w, a7, p.x, p.y, p.z, p.w, parea);
        float va = v0; int ia = g;
        if (v1 > va) { va = v1; ia = g + 1; }
        float vb = v2; int ib = g + 2;
        if (v3 > vb) { vb = v3; ib = g + 3; }
        if (vb > va) { va = vb; ia = ib; }
        float vc = v4; int ic = g + 4;
        if (v5 > vc) { vc = v5; ic = g + 5; }
        float vd = v6; int id_ = g + 6;
        if (v7 > vd) { vd = v7; id_ = g + 7; }
        if (vd > vc) { vc = vd; ic = id_; }
        if (vc > va) { va = vc; ia = ic; }
        if (va > bestiou) { bestiou = va; bi = ia; }
    }
    for (; g < G; ++g) {
        float4 gb = sgt[g];
        float v = iou_pair(gb.x, gb.y, gb.z, gb.w, sga[g], p.x, p.y, p.z, p.w, parea);
        if (v > bestiou) { bestiou = v; bi = g; }
    }

    float qcx = t.x * pw + pcx, qcy = t.y * ph + pcy;
    float qw = expf(t.z) * pw, qh = expf(t.w) * ph;
    float bx1 = fminf(fmaxf(qcx - 0.5f * qw, 0.f), W);
    float by1 = fminf(fmaxf(qcy - 0.5f * qh, 0.f), H);
    float bx2 = fminf(fmaxf(qcx + 0.5f * qw, 0.f), W);
    float by2 = fminf(fmaxf(qcy + 0.5f * qh, 0.f), H);
    f32x4 bp = {bx1, by1, bx2, by2};
    __builtin_nontemporal_store(bp, (f32x4*)&box_per[i]);

    float4 mg = sgt[bi];
    float gw = mg.z - mg.x, gh = mg.w - mg.y;
    float gcx = mg.x + 0.5f * gw, gcy = mg.y + 0.5f * gh;
    f32x4 rt = {(gcx - pcx) / pw, (gcy - pcy) / ph, logf(gw / pw), logf(gh / ph)};
    __builtin_nontemporal_store(rt, (f32x4*)(out + 4 * (size_t)(TOPK + i)));
}

// 256 blocks: per-chunk sums via device-scope atomics; LAST block runs the
// threshold-bin scan in-block (hist addressed through hperm).
__global__ __launch_bounds__(256) void k_hsum_scan(const u32* __restrict__ hist,
                                                   u32* __restrict__ csum,
                                                   u32* __restrict__ meta) {
    __shared__ u32 ps[4];
    __shared__ u32 S[NCHUNK];
    __shared__ u32 sh_tc, sh_E;
    __shared__ int slast;
    int b = blockIdx.x, t = threadIdx.x;

    u32 v = hist[(size_t)t * 256 + b];  // hperm(b*256+t)
#pragma unroll
    for (int o = 32; o; o >>= 1) v += __shfl_xor(v, o);
    if ((t & 63) == 0) ps[t >> 6] = v;
    __syncthreads();
    if (t == 0) {
        u32 tot = ps[0] + ps[1] + ps[2] + ps[3];
        atomicAdd(&csum[b], tot);
        __threadfence();
        u32 old = atomicAdd(&meta[62], 1u);
        slast = (old == NCHUNK - 1u) ? 1 : 0;
    }
    __syncthreads();
    if (!slast) return;

    u32 c = atomicAdd(&csum[t], 0u);
    S[t] = c;
    __syncthreads();
    for (int off = 1; off < NCHUNK; off <<= 1) {
        u32 x = (t + off < NCHUNK) ? S[t + off] : 0u;
        __syncthreads();
        S[t] += x;
        __syncthreads();
    }
    u32 suff = S[t];
    u32 E = suff - c;
    if (suff >= TOPK && E < TOPK) { sh_tc = (u32)t; sh_E = E; }
    __syncthreads();
    u32 tc = sh_tc, E0 = sh_E;
    u32 hh = hist[(size_t)t * 256 + tc];  // hperm(tc*256+t)
    __syncthreads();
    S[t] = hh;
    __syncthreads();
    for (int off = 1; off < NCHUNK; off <<= 1) {
        u32 x = (t + off < NCHUNK) ? S[t + off] : 0u;
        __syncthreads();
        S[t] += x;
        __syncthreads();
    }
    u32 tot2 = E0 + S[t];
    if (tot2 >= TOPK && (tot2 - hh) < TOPK) meta[0] = tc * 256u + (u32)t;
}

__global__ __launch_bounds__(256) void k_compact(const u32* __restrict__ score_bits,
                                                 const u32* __restrict__ meta, u32* __restrict__ cnt,
                                                 u64* __restrict__ keys, int N) {
    int i = blockIdx.x * 256 + threadIdx.x;
    if (i >= N) return;
    u32 b = score_bits[i];
    if ((b >> HSHIFT) >= meta[0]) {
        u32 pos = atomicAdd(cnt, 1u);
        if (pos < CAND_CAP) keys[pos] = ((u64)b << 32) | (u32)(~(u32)i);
    }
}

// Rank partials: 256 blocks = 16 i-tiles x 16 j-slices.
__global__ __launch_bounds__(256) void k_rank1(const u64* __restrict__ keys,
                                               const u32* __restrict__ meta,
                                               u32* __restrict__ rank) {
    __shared__ u64 sk[256];
    int it = blockIdx.x & 15, js = blockIdx.x >> 4;
    int t = threadIdx.x;
    u32 M = meta[1];
    if (M > CAND_CAP) M = CAND_CAP;
    u32 Mp = (M + 63u) & ~63u;
    u32 j0 = (u32)js * 256u;
    if (j0 >= Mp) return;
    u32 jn = Mp - j0; if (jn > 256u) jn = 256u;
    sk[t] = ((u32)t < jn && j0 + t < M) ? keys[j0 + t] : 0ull;
    __syncthreads();
    int idx = it * 256 + t;
    u64 k = (idx < (int)M) ? keys[idx] : ~0ull;
    u32 r = 0;
    int lane = t & 63;
    for (u32 jj = 0; jj < jn; jj += 64) {
        u64 tv = sk[jj + lane];
        u32 tlo = (u32)tv, thi = (u32)(tv >> 32);
#pragma unroll
        for (int l = 0; l < 64; ++l) {
            u64 kj = ((u64)(u32)__builtin_amdgcn_readlane(thi, l) << 32) |
                     (u64)(u32)__builtin_amdgcn_readlane(tlo, l);
            r += (kj > k) ? 1u : 0u;
        }
    }
    if (idx < (int)M && r) atomicAdd(&rank[idx], r);
}

__global__ __launch_bounds__(256) void k_rank2(const u64* __restrict__ keys,
                                               const u32* __restrict__ meta,
                                               const u32* __restrict__ rank,
                                               const float4* __restrict__ box_per,
                                               float4* __restrict__ topbox) {
    int idx = blockIdx.x * 256 + threadIdx.x;
    u32 M = meta[1];
    if (M > CAND_CAP) M = CAND_CAP;
    if (idx >= (int)M) return;
    u32 r = rank[idx];
    if (r < TOPK) {
        u64 k = keys[idx];
        topbox[r] = box_per[~(u32)(k & 0xffffffffull)];
    }
}

// Suppression mask, ROW-major (R8-exact): mask[i*32+w] bit jj set iff
// j=w*64+jj>i, j<TOPK, iou>thr. w block-uniform (topbox[j] broadcast loads).
__global__ __launch_bounds__(256) void k_mask(const float4* __restrict__ topbox,
                                              u64* __restrict__ mask) {
#pragma clang fp contract(off)
    int gid = blockIdx.x * 256 + threadIdx.x;  // 32 * TPAD threads
    int w = gid >> 11, i = gid & (TPAD - 1);
    u64 m = 0;
    int j0 = w << 6;
    if (i < TOPK && j0 + 63 > i) {
        float4 a = topbox[i];
        float aarea = (a.z - a.x) * (a.w - a.y);
        for (int jj = 0; jj < 64; ++jj) {
            int j = j0 + jj;
            if (j < TOPK && j > i) {
                float4 b = topbox[j];
                float barea = (b.z - b.x) * (b.w - b.y);
                float v = iou_pair(a.x, a.y, a.z, a.w, aarea, b.x, b.y, b.z, b.w, barea);
                if (v > NMS_THR) m |= (1ull << jj);
            }
        }
    }
    mask[(size_t)i * 32 + w] = m;
}

// Greedy NMS: R8's proven structure (70.9us) with ONE surgical change: the
// two per-step cross-lane readlanes (v_readlane of word c from the freshly
// loaded row -- VALU->SALU hazard stalls on the serial chain) are replaced by
// a SECOND prefetch ring dring[] holding buf[row*32 + c]: wave-uniform
// address -> broadcast ds_read (conflict-free), prefetched 8-ahead exactly
// like the row ring, so it's OFF the serial chain. Chain per step is now just
// bit->mk->4 masked ORs. R9's diag/phase-split restructure (86us, readlane
// hazards + VALU-latency chain) is reverted.
__global__ __launch_bounds__(256) void k_nms(const u64* __restrict__ mask,
                                             const float4* __restrict__ topbox,
                                             float* __restrict__ out) {
    __shared__ u64 sm[2][64 * 32];  // 2 x 16 KB double buffer
    __shared__ u64 srem[32];
    int t = threadIdx.x;
    int lane = t & 63;
    u32 lw = (u32)(lane & 31);
    u32 rlo = 0, rhi = 0;  // lane w of wave 0 holds removed word w

    // stage chunk 0: all 256 threads, 4 unconditional uint4 each
    {
        const uint4* __restrict__ src = (const uint4*)mask;
        uint4 v0 = src[t], v1 = src[t + 256], v2 = src[t + 512], v3 = src[t + 768];
        uint4* __restrict__ dst = (uint4*)sm[0];
        dst[t] = v0; dst[t + 256] = v1; dst[t + 512] = v2; dst[t + 768] = v3;
    }
    __syncthreads();

    for (int c = 0; c < 32; ++c) {
        if (t >= 64 && t < 192) {
            if (c + 1 < 32) {
                const uint4* __restrict__ src = (const uint4*)(mask + (size_t)(c + 1) * 2048);
                uint4* __restrict__ dst = (uint4*)sm[(c + 1) & 1];
                int u = t - 64;  // 0..127; 8 unconditional slots cover 1024 uint4
                uint4 v0 = src[u];
                uint4 v1 = src[u + 128];
                uint4 v2 = src[u + 256];
                uint4 v3 = src[u + 384];
                uint4 v4 = src[u + 512];
                uint4 v5 = src[u + 640];
                uint4 v6 = src[u + 768];
                uint4 v7 = src[u + 896];
                dst[u] = v0;
                dst[u + 128] = v1;
                dst[u + 256] = v2;
                dst[u + 384] = v3;
                dst[u + 512] = v4;
                dst[u + 640] = v5;
                dst[u + 768] = v6;
                dst[u + 896] = v7;
            }
        } else if (t < 64) {
            const u64* __restrict__ buf = sm[c & 1];
            u32 d_lo = (u32)__builtin_amdgcn_readlane(rlo, c);
            u32 d_hi = (u32)__builtin_amdgcn_readlane(rhi, c);
            u64 ring[8], dring[8];
#pragma unroll
            for (int p = 0; p < 8; ++p) {
                ring[p] = buf[p * 32 + lw];
                dring[p] = buf[p * 32 + c];   // uniform addr -> broadcast read
            }
#pragma unroll
            for (int l = 0; l < 64; ++l) {
                u64 row = ring[l & 7];
                u64 dg = dring[l & 7];
                if (l < 56) {
                    ring[l & 7] = buf[(l + 8) * 32 + lw];
                    dring[l & 7] = buf[(l + 8) * 32 + c];
                }
                u32 sc_lo = (u32)dg, sc_hi = (u32)(dg >> 32);  // == old readlane vals
                u32 bit = (l < 32) ? ((d_lo >> l) & 1u) : ((d_hi >> (l - 32)) & 1u);
                u32 mk = bit - 1u;  // keep (bit=0) -> all-ones
                d_lo |= sc_lo & mk;
                d_hi |= sc_hi & mk;
                rlo |= (u32)row & mk;
                rhi |= (u32)(row >> 32) & mk;
            }
        }
        __syncthreads();
    }
    if (t < 32) srem[t] = ((u64)rhi << 32) | rlo;
    __syncthreads();
    for (int r = t; r < TOPK; r += 256) {
        bool sup = (srem[r >> 6] >> (r & 63)) & 1ull;
        float4 b = topbox[r];
        ((float4*)out)[r] = sup ? make_float4(0.f, 0.f, 0.f, 0.f) : b;
    }
}

extern "C" void kernel_launch(void* const* d_in, const int* in_sizes, int n_in,
                              void* d_out, int out_size, void* d_ws, size_t ws_size,
                              hipStream_t stream) {
    const float* prop = (const float*)d_in[0];
    const float* btp = (const float*)d_in[1];
    const float* cls = (const float*)d_in[2];
    const float* gt = (const float*)d_in[3];
    const int* hptr = (const int*)d_in[4];
    const int* wptr = (const int*)d_in[5];
    float* out = (float*)d_out;
    int N = in_sizes[0] / 4;
    int G = in_sizes[3] / 4;
    if (G > 256) G = 256;

    char* ws = (char*)d_ws;
    size_t o = 0;
    u32* hist = (u32*)(ws + o);       o += (size_t)HBINS * 4;
    u32* csum = (u32*)(ws + o);       o += NCHUNK * 4;
    u32* meta = (u32*)(ws + o);       o += 256;
    u32* rank = (u32*)(ws + o);       o += (size_t)CAND_CAP * 4;
    u32* score_bits = (u32*)(ws + o); o += (((size_t)N * 4 + 255) & ~(size_t)255);
    u64* keys = (u64*)(ws + o);       o += (size_t)CAND_CAP * 8;
    float4* box_per = (float4*)(ws + o); o += (size_t)N * 16;
    float4* topbox = (float4*)(ws + o);  o += (size_t)TPAD * 16;
    u64* mask = (u64*)(ws + o);       o += (size_t)TPAD * 32 * 8;
    float* clsT = (float*)(ws + o);   o += (size_t)N * NCLS * 4;
    (void)o; (void)ws_size; (void)n_in; (void)out_size;

    int nb = (N + 255) / 256;
    k_prep<<<nb, 256, 0, stream>>>(cls, clsT, hist, csum, meta, rank, N);
    k_main<<<nb, 256, 0, stream>>>(prop, btp, clsT, gt, hptr, wptr, out, box_per, score_bits,
                                   hist, N, G);
    k_hsum_scan<<<NCHUNK, 256, 0, stream>>>(hist, csum, meta);
    k_compact<<<nb, 256, 0, stream>>>(score_bits, meta, meta + 1, keys, N);
    k_rank1<<<256, 256, 0, stream>>>(keys, meta, rank);
    k_rank2<<<CAND_CAP / 256, 256, 0, stream>>>(keys, meta, rank, box_per, topbox);
    k_mask<<<(32 * TPAD) / 256, 256, 0, stream>>>(topbox, mask);
    k_nms<<<1, 256, 0, stream>>>(mask, topbox, out);
}